// Round 4
// baseline (81.786 us; speedup 1.0000x reference)
//
#include <hip/hip_runtime.h>
#include <math.h>

#define NE 64
#define ND 512
#define NH 1024
#define NT 256
#define NC 8            // token chunk (compile-time -> full unroll)
#define NCH 16          // H-chunks
#define CHROWS (NH/NCH) // 64 rows per chunk

// ws layout: partial[NCH][NT][ND] floats = 16*256*512*4 = 8 MB

__device__ __forceinline__ int build_group(const int* __restrict__ idx, int e,
                                           int* tok_lds, int* wsum) {
    const int t = threadIdx.x, wave = t >> 6, lane = t & 63;
    const bool m = (idx[t] == e);
    const unsigned long long mask = __ballot(m);
    if (lane == 0) wsum[wave] = __popcll(mask);
    __syncthreads();
    int before = 0;
#pragma unroll
    for (int w = 0; w < 3; ++w) before += (w < wave) ? wsum[w] : 0;
    const int nt = wsum[0] + wsum[1] + wsum[2] + wsum[3];
    if (m) {
        int pos = before + __popcll(mask & ((1ull << lane) - 1ull));
        tok_lds[pos] = t;
    }
    __syncthreads();
    // pad so fragment loads are unconditional (dupes of token 0; stores stay
    // guarded by nt, so pad results are discarded)
    if (nt > 0 && t >= nt && t < nt + NC) tok_lds[t] = tok_lds[0];
    __syncthreads();
    return nt;
}

// Fused butterfly over 8 accumulators. Stages xor1/2/4 fold 8->1, then xor8
// completes the sum within each 16-lane group. Lane l then holds the full
// 16-lane-group sum for token t = bitrev3(l&7) (duplicated across l&8).
__device__ __forceinline__ float fused_reduce_16(float v[NC], int lane) {
#pragma unroll
    for (int i = 0; i < 4; ++i) {
        float lo = v[i], hi = v[i + 4];
        float send = (lane & 1) ? lo : hi;
        float recv = __shfl_xor(send, 1);
        v[i] = ((lane & 1) ? hi : lo) + recv;
    }
#pragma unroll
    for (int i = 0; i < 2; ++i) {
        float lo = v[i], hi = v[i + 2];
        float send = (lane & 2) ? lo : hi;
        float recv = __shfl_xor(send, 2);
        v[i] = ((lane & 2) ? hi : lo) + recv;
    }
    {
        float lo = v[0], hi = v[1];
        float send = (lane & 4) ? lo : hi;
        float recv = __shfl_xor(send, 4);
        v[0] = ((lane & 4) ? hi : lo) + recv;
    }
    v[0] += __shfl_xor(v[0], 8);
    return v[0];
}

// ...continue to a full 64-lane reduction (for fc1's K=512-per-row dots).
__device__ __forceinline__ float fused_reduce_64(float v[NC], int lane) {
    float p = fused_reduce_16(v, lane);
    p += __shfl_xor(p, 16);
    p += __shfl_xor(p, 32);
    return p;
}

// One block = (expert e, H-chunk ch of 64 rows).
// Phase A (fc1): 4 waves x 16 rows; wave-wide K=512 dot, h-chunk -> LDS.
// Phase B (fc2 split-K): partial[ch][t][d] = sum_{j in chunk} h[t][j]*w2[d][j]
// for ALL d; wave w owns d in [w*128, w*128+128), 4 d-rows per iteration.
__global__ __launch_bounds__(256) void moe_fused_kernel(
    const float* __restrict__ x, const float* __restrict__ w1,
    const float* __restrict__ w2, const int* __restrict__ idx,
    float* __restrict__ partial) {
    __shared__ int tok_lds[NT + NC];
    __shared__ int wsum[4];
    __shared__ float hs[NC][CHROWS];   // 2 KB

    const int e  = blockIdx.x >> 4;
    const int ch = blockIdx.x & 15;
    const int tid = threadIdx.x, wave = tid >> 6, lane = tid & 63;
    const int nt = build_group(idx, e, tok_lds, wsum);
    if (nt == 0) return;

    const float* w1e = w1 + (size_t)e * NH * ND;
    const float* w2e = w2 + (size_t)e * ND * NH;
    const int j0 = ch * CHROWS;          // chunk base row in H
    const int jw = j0 + wave * 16;       // this wave's 16 fc1 rows

    for (int base = 0; base < nt; base += NC) {
        // ---------------- Phase A: fc1 ----------------
        float4 xa[NC], xb[NC];
#pragma unroll
        for (int t = 0; t < NC; ++t) {
            const float* xr = x + (size_t)tok_lds[base + t] * ND;
            xa[t] = *(const float4*)(xr + lane * 4);
            xb[t] = *(const float4*)(xr + 256 + lane * 4);
        }
#pragma unroll 4
        for (int r = 0; r < 16; ++r) {
            const float* wr = w1e + (size_t)(jw + r) * ND;
            const float4 wa = *(const float4*)(wr + lane * 4);
            const float4 wb = *(const float4*)(wr + 256 + lane * 4);
            float acc[NC];
#pragma unroll
            for (int t = 0; t < NC; ++t) {
                acc[t] = wa.x * xa[t].x + wa.y * xa[t].y + wa.z * xa[t].z + wa.w * xa[t].w
                       + wb.x * xb[t].x + wb.y * xb[t].y + wb.z * xb[t].z + wb.w * xb[t].w;
            }
            float p = fused_reduce_64(acc, lane);
            if (lane < NC) {
                int t = ((lane & 1) << 2) | (lane & 2) | ((lane >> 2) & 1);
                // write h for ALL 8 slots (pad slots = dup of token 0: finite,
                // discarded at phase-B store)
                hs[t][wave * 16 + r] = p / (1.0f + __expf(-p));
            }
        }
        __syncthreads();   // hs complete

        // ---------------- Phase B: fc2 split-K ----------------
        // per-lane h fragment: j4 = (lane&15)*4, all 8 tokens (reused 32 iters)
        float4 hf[NC];
#pragma unroll
        for (int t = 0; t < NC; ++t)
            hf[t] = *(const float4*)&hs[t][(lane & 15) * 4];

        const int dw = wave * 128 + (lane >> 4);   // this lane's d-row offset
#pragma unroll 4
        for (int it = 0; it < 32; ++it) {
            const int d = dw + it * 4;
            const float4 wv = *(const float4*)(w2e + (size_t)d * NH + j0 + (lane & 15) * 4);
            float acc[NC];
#pragma unroll
            for (int t = 0; t < NC; ++t) {
                acc[t] = wv.x * hf[t].x + wv.y * hf[t].y + wv.z * hf[t].z + wv.w * hf[t].w;
            }
            float p = fused_reduce_16(acc, lane);
            if ((lane & 8) == 0) {
                int t = ((lane & 1) << 2) | (lane & 2) | ((lane >> 2) & 1);
                if (base + t < nt) {
                    int tk = tok_lds[base + t];
                    partial[((size_t)ch * NT + tk) * ND + d] = p;
                }
            }
        }
        __syncthreads();   // hs reused next chunk
    }
}

// out[t][d] = sum_c partial[c][t][d]; 8 MB read (L2/LLC-resident), 0.5 MB write
__global__ __launch_bounds__(256) void sum_kernel(
    const float* __restrict__ partial, float* __restrict__ out) {
    const int i = blockIdx.x * 256 + threadIdx.x;   // float4 index over [NT*ND/4)
    const float4* p = (const float4*)partial;
    float4 s = p[i];
#pragma unroll
    for (int c = 1; c < NCH; ++c) {
        float4 v = p[(size_t)c * (NT * ND / 4) + i];
        s.x += v.x; s.y += v.y; s.z += v.z; s.w += v.w;
    }
    ((float4*)out)[i] = s;
}

extern "C" void kernel_launch(void* const* d_in, const int* in_sizes, int n_in,
                              void* d_out, int out_size, void* d_ws, size_t ws_size,
                              hipStream_t stream) {
    const float* x    = (const float*)d_in[0];
    const int*   eidx = (const int*)d_in[1];
    const float* fc1w = (const float*)d_in[2];
    const float* fc2w = (const float*)d_in[3];
    float* out     = (float*)d_out;
    float* partial = (float*)d_ws;   // 8 MB

    moe_fused_kernel<<<NE * NCH, 256, 0, stream>>>(x, fc1w, fc2w, eidx, partial);
    sum_kernel<<<(NT * ND / 4) / 256, 256, 0, stream>>>(partial, out);
}

// Round 5
// 61.188 us; speedup vs baseline: 1.3366x; 1.3366x over previous
//
#include <hip/hip_runtime.h>
#include <math.h>

#define NE 64
#define ND 512
#define NH 1024
#define NT 256
#define NC 8   // token chunk per W-pass (covers nt<=8 in one weight stream)

// ws layout: h[NT*NH] floats

__device__ __forceinline__ int build_group(const int* __restrict__ idx, int e,
                                           int* tok_lds, int* wsum) {
    const int t = threadIdx.x, wave = t >> 6, lane = t & 63;
    const bool m = (idx[t] == e);
    const unsigned long long mask = __ballot(m);
    if (lane == 0) wsum[wave] = __popcll(mask);
    __syncthreads();
    int before = 0;
#pragma unroll
    for (int w = 0; w < 3; ++w) before += (w < wave) ? wsum[w] : 0;
    const int nt = wsum[0] + wsum[1] + wsum[2] + wsum[3];
    if (m) {
        int pos = before + __popcll(mask & ((1ull << lane) - 1ull));
        tok_lds[pos] = t;
    }
    __syncthreads();
    // pad so fragment loads are unconditional (dupes of token 0; stores stay
    // guarded by nt, so pad results are discarded)
    if (nt > 0 && t >= nt && t < nt + NC) tok_lds[t] = tok_lds[0];
    __syncthreads();
    return nt;
}

// Fused butterfly over 8 accumulators: 10 shuffles, depth 6, for 8 full
// 64-lane reductions. On exit lanes 0..7 hold the sum for token bitrev3(lane).
__device__ __forceinline__ float fused_reduce8_64(float v[NC], int lane) {
#pragma unroll
    for (int i = 0; i < 4; ++i) {
        float lo = v[i], hi = v[i + 4];
        float send = (lane & 1) ? lo : hi;
        float recv = __shfl_xor(send, 1);
        v[i] = ((lane & 1) ? hi : lo) + recv;
    }
#pragma unroll
    for (int i = 0; i < 2; ++i) {
        float lo = v[i], hi = v[i + 2];
        float send = (lane & 2) ? lo : hi;
        float recv = __shfl_xor(send, 2);
        v[i] = ((lane & 2) ? hi : lo) + recv;
    }
    {
        float lo = v[0], hi = v[1];
        float send = (lane & 4) ? lo : hi;
        float recv = __shfl_xor(send, 4);
        v[0] = ((lane & 4) ? hi : lo) + recv;
    }
    v[0] += __shfl_xor(v[0], 8);
    v[0] += __shfl_xor(v[0], 16);
    v[0] += __shfl_xor(v[0], 32);
    return v[0];
}

// Fused butterfly over 4 accumulators -> full 64-lane sums.
// On exit lane l holds the sum for token t = 2*(l&1) + ((l>>1)&1).
__device__ __forceinline__ float fused_reduce4_64(float v[4], int lane) {
#pragma unroll
    for (int i = 0; i < 2; ++i) {
        float lo = v[i], hi = v[i + 2];
        float send = (lane & 1) ? lo : hi;
        float recv = __shfl_xor(send, 1);
        v[i] = ((lane & 1) ? hi : lo) + recv;
    }
    {
        float lo = v[0], hi = v[1];
        float send = (lane & 2) ? lo : hi;
        float recv = __shfl_xor(send, 2);
        v[0] = ((lane & 2) ? hi : lo) + recv;
    }
    v[0] += __shfl_xor(v[0], 4);
    v[0] += __shfl_xor(v[0], 8);
    v[0] += __shfl_xor(v[0], 16);
    v[0] += __shfl_xor(v[0], 32);
    return v[0];
}

// fc1: grid = NE*32; block owns 32 H-rows (4 waves x 8 rows).
// Lane covers k in [4l,4l+4) and [256+4l,256+4l+4)  (coalesced 1KB/instr).
__global__ __launch_bounds__(256) void fc1_kernel(
    const float* __restrict__ x, const float* __restrict__ w1,
    const int* __restrict__ idx, float* __restrict__ h) {
    __shared__ int tok_lds[NT + NC];
    __shared__ int wsum[4];
    const int e  = blockIdx.x >> 5;
    const int ch = blockIdx.x & 31;
    const int tid = threadIdx.x, wave = tid >> 6, lane = tid & 63;
    const int nt = build_group(idx, e, tok_lds, wsum);
    if (nt == 0) return;
    const float* w1e = w1 + (size_t)e * NH * ND;
    const int jw = ch * 32 + wave * 8;

    for (int base = 0; base < nt; base += NC) {
        float4 xa[NC], xb[NC];
#pragma unroll
        for (int t = 0; t < NC; ++t) {
            const float* xr = x + (size_t)tok_lds[base + t] * ND;
            xa[t] = *(const float4*)(xr + lane * 4);
            xb[t] = *(const float4*)(xr + 256 + lane * 4);
        }
#pragma unroll 4
        for (int r = 0; r < 8; ++r) {
            const float* wr = w1e + (size_t)(jw + r) * ND;
            const float4 wa = *(const float4*)(wr + lane * 4);
            const float4 wb = *(const float4*)(wr + 256 + lane * 4);
            float acc[NC];
#pragma unroll
            for (int t = 0; t < NC; ++t) {
                acc[t] = wa.x * xa[t].x + wa.y * xa[t].y + wa.z * xa[t].z + wa.w * xa[t].w
                       + wb.x * xb[t].x + wb.y * xb[t].y + wb.z * xb[t].z + wb.w * xb[t].w;
            }
            float p = fused_reduce8_64(acc, lane);
            if (lane < NC) {
                int t = ((lane & 1) << 2) | (lane & 2) | ((lane >> 2) & 1);
                if (base + t < nt) {
                    int tk = tok_lds[base + t];
                    float s = p / (1.0f + __expf(-p));
                    h[(size_t)tk * NH + (jw + r)] = s;
                }
            }
        }
    }
}

// fc2: grid = NE*32; block owns 16 D-rows. Token-split across wave pairs:
// waves {0,1} handle tokens 0-3 of the chunk, waves {2,3} tokens 4-7;
// wave&1 picks the 8-row half. W2 rows are read twice per block (second
// reader hits L1); h fragments are 16 float4/lane -> ~100 VGPR.
__global__ __launch_bounds__(256) void fc2_kernel(
    const float* __restrict__ h, const float* __restrict__ w2,
    const int* __restrict__ idx, float* __restrict__ out) {
    __shared__ int tok_lds[NT + NC];
    __shared__ int wsum[4];
    const int e  = blockIdx.x >> 5;
    const int ch = blockIdx.x & 31;
    const int tid = threadIdx.x, wave = tid >> 6, lane = tid & 63;
    const int nt = build_group(idx, e, tok_lds, wsum);
    if (nt == 0) return;
    const float* w2e = w2 + (size_t)e * ND * NH;
    const int tokhalf = wave >> 1;                 // 0: tokens 0-3, 1: tokens 4-7
    const int d0 = ch * 16 + (wave & 1) * 8;       // 8 rows per wave

    for (int base = 0; base < nt; base += NC) {
        if (base + tokhalf * 4 >= nt) break;       // wave pair has no real tokens
        float4 hb0[4], hb1[4], hb2[4], hb3[4];
#pragma unroll
        for (int t = 0; t < 4; ++t) {
            const float* hr = h + (size_t)tok_lds[base + tokhalf * 4 + t] * NH;
            hb0[t] = *(const float4*)(hr + lane * 4);
            hb1[t] = *(const float4*)(hr + 256 + lane * 4);
            hb2[t] = *(const float4*)(hr + 512 + lane * 4);
            hb3[t] = *(const float4*)(hr + 768 + lane * 4);
        }
#pragma unroll 4
        for (int r = 0; r < 8; ++r) {
            const float* wr = w2e + (size_t)(d0 + r) * NH;
            const float4 w0 = *(const float4*)(wr + lane * 4);
            const float4 w1v = *(const float4*)(wr + 256 + lane * 4);
            const float4 w2v = *(const float4*)(wr + 512 + lane * 4);
            const float4 w3v = *(const float4*)(wr + 768 + lane * 4);
            float acc[4];
#pragma unroll
            for (int t = 0; t < 4; ++t) {
                acc[t] = w0.x * hb0[t].x + w0.y * hb0[t].y + w0.z * hb0[t].z + w0.w * hb0[t].w
                       + w1v.x * hb1[t].x + w1v.y * hb1[t].y + w1v.z * hb1[t].z + w1v.w * hb1[t].w
                       + w2v.x * hb2[t].x + w2v.y * hb2[t].y + w2v.z * hb2[t].z + w2v.w * hb2[t].w
                       + w3v.x * hb3[t].x + w3v.y * hb3[t].y + w3v.z * hb3[t].z + w3v.w * hb3[t].w;
            }
            float p = fused_reduce4_64(acc, lane);
            if (lane < 4) {
                int t = ((lane & 1) << 1) | ((lane >> 1) & 1);
                int slot = base + tokhalf * 4 + t;
                if (slot < nt) {
                    int tk = tok_lds[slot];
                    out[(size_t)tk * ND + (d0 + r)] = p;
                }
            }
        }
    }
}

extern "C" void kernel_launch(void* const* d_in, const int* in_sizes, int n_in,
                              void* d_out, int out_size, void* d_ws, size_t ws_size,
                              hipStream_t stream) {
    const float* x    = (const float*)d_in[0];
    const int*   eidx = (const int*)d_in[1];
    const float* fc1w = (const float*)d_in[2];
    const float* fc2w = (const float*)d_in[3];
    float* out = (float*)d_out;
    float* h   = (float*)d_ws;

    fc1_kernel<<<NE * 32, 256, 0, stream>>>(x, fc1w, eidx, h);
    fc2_kernel<<<NE * 32, 256, 0, stream>>>(h, fc2w, eidx, out);
}